// Round 21
// baseline (293.042 us; speedup 1.0000x reference)
//
#include <hip/hip_runtime.h>

typedef _Float16 f16;
typedef f16 f16x8 __attribute__((ext_vector_type(8)));
typedef __fp16 h2v __attribute__((ext_vector_type(2)));
typedef float f32x4 __attribute__((ext_vector_type(4)));
typedef float f32x16 __attribute__((ext_vector_type(16)));
typedef unsigned int uint;
typedef unsigned short ushort;
typedef unsigned long long ull;

#define NCH 16
#define NB 32
#define NH 256
#define NW 256
#define HW 65536
#define CHW 1048576

#define BIAS_BYTE 90112
#define WS_BYTES 91648
#define BAND_ROWS 5
#define STAGE_ROWS 7
#define XBAND_OFF WS_BYTES                    // 91648
#define XBAND_BYTES (STAGE_ROWS*256*32)       // 57344
#define LIST_MAX 1280
#define LIST_OFF (XBAND_OFF + XBAND_BYTES)    // 148992 (2 buffers x 2560 B)
#define FLAG_OFF (LIST_OFF + 2*LIST_MAX*2)    // 154112 (2 buffers x 1280 B)
#define NACT_OFF (FLAG_OFF + 2*1280)          // 156672
#define LDS_TOTAL (NACT_OFF + 16)             // 156688 <= 163840
#define NBANDS_PER_IMG 52
#define NBANDS_TOTAL (NB*NBANDS_PER_IMG)      // 1664
#define NRECS (STAGE_ROWS*2*256)              // 3584

__global__ void prep_k(const float* __restrict__ w1, const float* __restrict__ w2,
                       const float* __restrict__ w3, const float* __restrict__ w4,
                       const float* __restrict__ b1, const float* __restrict__ b2,
                       const float* __restrict__ b3, float* __restrict__ wsf) {
  f16* wf = (f16*)wsf;
  int id = blockIdx.x * 256 + threadIdx.x;
  if (id < 8192) {
    int j = id & 7, l = (id >> 3) & 63, mt = (id >> 9) & 3, kt = id >> 11;
    int o = mt * 32 + (l & 31), c = kt * 16 + (l >> 5) * 8 + j;
    wf[id] = (f16)w1[o * 64 + c];
  } else if (id < 24576) {
    int t = id - 8192;
    int j = t & 7, l = (t >> 3) & 63, mt = (t >> 9) & 3, kt = t >> 11;
    int o = mt * 32 + (l & 31), c = kt * 16 + (l >> 5) * 8 + j;
    wf[8192 + t] = (f16)w2[o * 128 + c];
  } else if (id < 40960) {
    int t = id - 24576;
    int j = t & 7, l = (t >> 3) & 63, mt = (t >> 9) & 3, kt = t >> 11;
    int o = mt * 32 + (l & 31), c = kt * 16 + (l >> 5) * 8 + j;
    wf[24576 + t] = (f16)w3[o * 128 + c];
  } else if (id < 45056) {
    int t = id - 40960;
    int j = t & 7, l = (t >> 3) & 63, kt = t >> 9;
    int m = l & 31, hh = l >> 5;
    int c = kt * 16 + hh * 8 + j;
    wf[40960 + t] = (m < 16) ? (f16)w4[m * 128 + c] : (f16)0.f;
  } else if (id < 45440) {
    int t = id - 45056;
    int r = t & 15, hh = (t >> 4) & 1, mt = (t >> 5) & 3, ly = t >> 7;
    const float* bb = (ly == 0) ? b1 : (ly == 1) ? b2 : b3;
    ((float*)((unsigned char*)wsf + BIAS_BYTE))[t] =
        bb[mt * 32 + (r & 3) + 8 * (r >> 2) + 4 * hh];
  }
}

__device__ __forceinline__ void pl32swap(uint& a, uint& b) {
  asm volatile("v_permlane32_swap_b32 %0, %1" : "+v"(a), "+v"(b));
}

__device__ __forceinline__ f16x8 mk8(uint a, uint b, uint c, uint d) {
  union { uint u[4]; f16x8 v; } z;
  z.u[0] = a; z.u[1] = b; z.u[2] = c; z.u[3] = d;
  return z.v;
}

template <int NKT>
__device__ __forceinline__ void gemm_half(const unsigned char* __restrict__ smem,
                                          int wfFragBase, int biasFloatOff, int lane, int hi,
                                          const f16x8* __restrict__ B, f32x16 acc[4]) {
#pragma unroll
  for (int mt = 0; mt < 4; ++mt) {
    const f32x16* bp =
        (const f32x16*)(smem + BIAS_BYTE + 4 * (biasFloatOff + (mt * 2 + hi) * 16));
    acc[mt] = *bp;
  }
  const f16x8* A = (const f16x8*)smem + wfFragBase + lane;
  __builtin_amdgcn_s_setprio(1);
#pragma unroll
  for (int kt = 0; kt < NKT; ++kt) {
#pragma unroll
    for (int mt = 0; mt < 4; ++mt) {
      f16x8 a = A[(kt * 4 + mt) * 64];
      acc[mt] = __builtin_amdgcn_mfma_f32_32x32x16_f16(a, B[kt], acc[mt], 0, 0, 0);
    }
  }
  __builtin_amdgcn_s_setprio(0);
}

__device__ __forceinline__ void epilogue_swap(const f32x16 acc[4], f16x8 Bn[8]) {
  uint w[32];
  const h2v c001 = {(__fp16)0.01f, (__fp16)0.01f};
#pragma unroll
  for (int mt = 0; mt < 4; ++mt) {
#pragma unroll
    for (int i = 0; i < 8; ++i) {
      h2v u = __builtin_amdgcn_cvt_pkrtz(acc[mt][2 * i], acc[mt][2 * i + 1]);
      h2v s = u * c001;
      h2v m = __builtin_elementwise_max(u, s);
      w[mt * 8 + i] = __builtin_bit_cast(uint, m);
    }
  }
#pragma unroll
  for (int kt = 0; kt < 8; ++kt) {
    int mt = kt >> 1, sub = kt & 1;
    int W = mt * 8 + sub * 4;
    uint a0 = w[W], a1 = w[W + 1], a2 = w[W + 2], a3 = w[W + 3];
    pl32swap(a0, a2);
    pl32swap(a1, a3);
    Bn[kt] = mk8(a0, a1, a2, a3);
  }
}

// perception from f16 band: 9 ds_read_b128; slot: half=(ch>>1)&1, j=(ch>>2)*2+(ch&1)
__device__ __forceinline__ void perc_band(const unsigned char* __restrict__ xband,
                                          int rl, int c, int hi, f16x8 B1h[4]) {
  const bool fL = c > 0, fR = c < NW - 1;
  const int cm = fL ? c - 1 : c, cp2 = fR ? c + 1 : c;
  const int swm = (hi ^ (cm & 1)) << 4;
  const int swc = (hi ^ (c & 1)) << 4;
  const int swp = (hi ^ (cp2 & 1)) << 4;
  union U4 { uint4 u; f16 hh[8]; };
  U4 q[9];
#pragma unroll
  for (int dr = 0; dr < 3; ++dr) {
    const unsigned char* rowp = xband + (size_t)(rl + dr) * 256 * 32;
    q[dr * 3 + 0].u = *(const uint4*)(rowp + cm * 32 + swm);
    q[dr * 3 + 1].u = *(const uint4*)(rowp + c * 32 + swc);
    q[dr * 3 + 2].u = *(const uint4*)(rowp + cp2 * 32 + swp);
  }
  uint yw[16];
#pragma unroll
  for (int j = 0; j < 8; ++j) {
    float v00 = (float)q[0].hh[j], v01 = (float)q[1].hh[j], v02 = (float)q[2].hh[j];
    float v10 = (float)q[3].hh[j], v11 = (float)q[4].hh[j], v12 = (float)q[5].hh[j];
    float v20 = (float)q[6].hh[j], v21 = (float)q[7].hh[j], v22 = (float)q[8].hh[j];
    if (!fL) { v00 = 0.f; v10 = 0.f; v20 = 0.f; }
    if (!fR) { v02 = 0.f; v12 = 0.f; v22 = 0.f; }
    float rs0 = v00 + v01 + v02, rs2 = v20 + v21 + v22;
    float fsx = (v02 - v00) + (v22 - v20) + 2.f * (v12 - v10);
    float fsy = (rs2 - rs0) + (v21 - v01);
    float flap = (rs0 + rs2 + v10 + v12) - 8.f * v11;
    h2v t0 = __builtin_amdgcn_cvt_pkrtz(v11, fsx);
    h2v t1 = __builtin_amdgcn_cvt_pkrtz(fsy, flap);
    int kt = j >> 1, cp = j & 1;
    yw[kt * 4 + cp * 2 + 0] = __builtin_bit_cast(uint, t0);
    yw[kt * 4 + cp * 2 + 1] = __builtin_bit_cast(uint, t1);
  }
#pragma unroll
  for (int kt = 0; kt < 4; ++kt)
    B1h[kt] = mk8(yw[kt * 4], yw[kt * 4 + 1], yw[kt * 4 + 2], yw[kt * 4 + 3]);
}

// load the 8 channels of one staging record (coalesced per wave) into a uint4
__device__ __forceinline__ uint4 load_rec(const float* __restrict__ xb, int r0,
                                          int e) {
  int col = e & 255;
  int pair = e >> 8;
  int sr = pair >> 1, h = pair & 1;
  int gr = r0 - 1 + sr;
  union { f16 hh[8]; uint4 u; } rc;
  if ((unsigned)gr < (unsigned)NH) {
#pragma unroll
    for (int j = 0; j < 8; ++j) {
      int ch = ((j >> 1) << 2) | (h << 1) | (j & 1);
      rc.hh[j] = (f16)xb[((size_t)ch << 16) + (gr << 8) + col];
    }
  } else {
    rc.u.x = 0; rc.u.y = 0; rc.u.z = 0; rc.u.w = 0;
  }
  return rc.u;
}

__device__ __forceinline__ void write_rec(unsigned char* __restrict__ xband, int e,
                                          uint4 r) {
  int col = e & 255;
  int pair = e >> 8;
  int sr = pair >> 1, h = pair & 1;
  *(uint4*)(xband + (size_t)(sr * 256 + col) * 32 + ((h ^ (col & 1)) << 4)) = r;
}

// compact one row's mask values (already in regs) into list/flags/ctr
__device__ __forceinline__ void compact_row(const float mv[4], int wv, int lane, int row,
                                            ushort* __restrict__ list,
                                            unsigned char* __restrict__ flags,
                                            int* __restrict__ ctr) {
  if (row >= NH) return;
  ull bal[4];
  int c = 0;
#pragma unroll
  for (int k = 0; k < 4; ++k) {
    bool a = mv[k] > 0.f;
    flags[wv * 256 + k * 64 + lane] = a ? 1 : 0;
    bal[k] = __ballot(a);
    c += __popcll(bal[k]);
  }
  int base;
  if (lane == 0) base = atomicAdd(ctr, c);
  base = __shfl(base, 0);
#pragma unroll
  for (int k = 0; k < 4; ++k) {
    int rank = __popcll(bal[k] & ((1ull << lane) - 1));
    if ((bal[k] >> lane) & 1ull)
      list[base + rank] = (ushort)((wv << 8) | (k * 64 + lane));
    base += __popcll(bal[k]);
  }
}

__global__ __launch_bounds__(1024, 1)
void nca_band_k(const float* __restrict__ x, const float* __restrict__ wsf,
                const float* __restrict__ mask, float* __restrict__ xn) {
  extern __shared__ unsigned char smem[];
  unsigned char* xband = smem + XBAND_OFF;
  ushort* listbuf = (ushort*)(smem + LIST_OFF);
  unsigned char* flagbuf = smem + FLAG_OFF;
  int* nacts = (int*)(smem + NACT_OFF);

  const int tid = threadIdx.x;
  const int lane = tid & 63;
  const int wv = tid >> 6;        // 0..15
  const int hi = lane >> 5;

  // ---- stage weights+bias once ----
  {
    const uint4* src = (const uint4*)wsf;
    uint4* dst = (uint4*)smem;
    for (int i = tid; i < WS_BYTES / 16; i += 1024) dst[i] = src[i];
  }
  if (tid < 2) nacts[tid] = 0;
  __syncthreads();

  // ---- prologue: stage + compact band0 directly (buffer 0) ----
  {
    const int band = blockIdx.x;
    const int b = band / NBANDS_PER_IMG, r0 = (band % NBANDS_PER_IMG) * BAND_ROWS;
    const float* xb = x + (size_t)b * CHW;
#pragma unroll
    for (int i = 0; i < 4; ++i) {
      int e = tid + i * 1024;
      if (e < NRECS) write_rec(xband, e, load_rec(xb, r0, e));
    }
    if (wv < BAND_ROWS) {
      int row = r0 + wv;
      float mv[4] = {0.f, 0.f, 0.f, 0.f};
      if (row < NH) {
        const float* mb = mask + (size_t)b * HW;
#pragma unroll
        for (int k = 0; k < 4; ++k) mv[k] = mb[(row << 8) + k * 64 + lane];
      }
      compact_row(mv, wv, lane, row, listbuf, flagbuf, &nacts[0]);
    }
  }
  __syncthreads();

  for (int band = blockIdx.x, t = 0; band < NBANDS_TOTAL; band += 256, ++t) {
    const int lb = t & 1;
    const int b = band / NBANDS_PER_IMG, r0 = (band % NBANDS_PER_IMG) * BAND_ROWS;
    const float* xb = x + (size_t)b * CHW;
    float* xnb = xn + (size_t)b * CHW;
    const ushort* list = listbuf + lb * LIST_MAX;
    const unsigned char* flags = flagbuf + lb * 1280;
    const int n = nacts[lb];

    // ---- step 1: prefetch next band (records + mask) into registers ----
    const int nxt = band + 256;
    const bool hasNext = nxt < NBANDS_TOTAL;
    uint4 rec[4];
    float nmv[4] = {0.f, 0.f, 0.f, 0.f};
    if (hasNext) {
      const int b2 = nxt / NBANDS_PER_IMG, nr0 = (nxt % NBANDS_PER_IMG) * BAND_ROWS;
      const float* nxb = x + (size_t)b2 * CHW;
#pragma unroll
      for (int i = 0; i < 4; ++i) {
        int e = tid + i * 1024;
        if (e < NRECS) rec[i] = load_rec(nxb, nr0, e);
      }
      if (wv < BAND_ROWS) {
        int row = nr0 + wv;
        if (row < NH) {
          const float* nmb = mask + (size_t)b2 * HW;
#pragma unroll
          for (int k = 0; k < 4; ++k) nmv[k] = nmb[(row << 8) + k * 64 + lane];
        }
      }
    }
    __builtin_amdgcn_sched_barrier(0);   // pin prefetch issue before compute

    // ---- step 2: dense inactive copy (xn = x), disjoint from MLP writes ----
#pragma unroll
    for (int i = 0; i < 20; ++i) {
      int e = tid + i * 1024;             // e < 20480 always
      int col = e & 255;
      int t2 = e >> 8;                    // 0..79
      int rl = t2 >> 4, ch = t2 & 15;
      int row = r0 + rl;
      if (row < NH && !flags[rl * 256 + col]) {
        size_t off = ((size_t)ch << 16) + (row << 8) + col;
        xnb[off] = xb[off];
      }
    }

    // ---- step 3: MLP on active batches ----
    const int nbatch = (n + 31) >> 5;
    for (int k = wv; k < nbatch; k += 16) {
      int idx = k * 32 + (lane & 31);
      if (idx >= n) idx = n - 1;
      const int entry = list[idx];
      const int rl = entry >> 8, c = entry & 255;

      f16x8 B1[4];
      perc_band(xband, rl, c, hi, B1);

      f32x16 acc[4];
      f16x8 B2[8], B3[8], B4[8];
      gemm_half<4>(smem, 0, 0, lane, hi, B1, acc);
      epilogue_swap(acc, B2);
      gemm_half<8>(smem, 1024, 128, lane, hi, B2, acc);
      epilogue_swap(acc, B3);
      gemm_half<8>(smem, 3072, 256, lane, hi, B3, acc);
      epilogue_swap(acc, B4);

      f32x16 a4;
#pragma unroll
      for (int r = 0; r < 16; ++r) a4[r] = 0.f;
      {
        const f16x8* A4 = (const f16x8*)smem + 5120 + lane;
        __builtin_amdgcn_s_setprio(1);
#pragma unroll
        for (int kt = 0; kt < 8; ++kt)
          a4 = __builtin_amdgcn_mfma_f32_32x32x16_f16(A4[kt * 64], B4[kt], a4, 0, 0, 0);
        __builtin_amdgcn_s_setprio(0);
      }

      {
        const int row = r0 + rl;
        const float* xrb = xb + (row << 8) + c;
        float* xob = xnb + (row << 8) + c;
#pragma unroll
        for (int r = 0; r < 8; ++r) {
          int ch = (r & 3) + 8 * (r >> 2) + 4 * hi;
          xob[(size_t)ch << 16] = xrb[(size_t)ch << 16] + a4[r];
        }
      }
    }

    if (tid == 0) nacts[lb ^ 1] = 0;     // reset BEFORE barrier (ordered vs step 5 atomics)
    __syncthreads();                     // xband/list/flags reads done

    // ---- step 5: write prefetched records + compact next band ----
    if (hasNext) {
      const int nr0 = ((band + 256) % NBANDS_PER_IMG) * BAND_ROWS;
#pragma unroll
      for (int i = 0; i < 4; ++i) {
        int e = tid + i * 1024;
        if (e < NRECS) write_rec(xband, e, rec[i]);
      }
      if (wv < BAND_ROWS) {
        int row = nr0 + wv;
        compact_row(nmv, wv, lane, row, listbuf + (lb ^ 1) * LIST_MAX,
                    flagbuf + (lb ^ 1) * 1280, &nacts[lb ^ 1]);
      }
      __syncthreads();                   // next band's LDS state ready
    }
  }
}

// alive factor: row-block with LDS horizontal-max sharing; zero dead pixels
__global__ void alive_scale_k(const float* __restrict__ x, float* __restrict__ xn) {
  __shared__ float pm[4][258];
  const int col = threadIdx.x;
  const int row = blockIdx.x;
  const int b = blockIdx.y;
  const float NEG = -3.0e38f;
  float v0 = NEG, v1 = NEG, v2 = NEG, v3 = NEG;
  const size_t base0 = (size_t)b * CHW + ((size_t)row << 8) + col;
#pragma unroll
  for (int dr = -1; dr <= 1; ++dr) {
    int rr = row + dr;
    if ((unsigned)rr < NH) {
      long o = (long)base0 + dr * NW;
      v0 = fmaxf(v0, x[o]);
      v1 = fmaxf(v1, x[o + HW]);
      v2 = fmaxf(v2, xn[o]);
      v3 = fmaxf(v3, xn[o + HW]);
    }
  }
  pm[0][col + 1] = v0;
  pm[1][col + 1] = v1;
  pm[2][col + 1] = v2;
  pm[3][col + 1] = v3;
  if (col == 0) {
#pragma unroll
    for (int f = 0; f < 4; ++f) { pm[f][0] = NEG; pm[f][257] = NEG; }
  }
  __syncthreads();
  float p0 = fmaxf(fmaxf(pm[0][col], pm[0][col + 1]), pm[0][col + 2]);
  float p1 = fmaxf(fmaxf(pm[1][col], pm[1][col + 1]), pm[1][col + 2]);
  float p2 = fmaxf(fmaxf(pm[2][col], pm[2][col + 1]), pm[2][col + 2]);
  float p3 = fmaxf(fmaxf(pm[3][col], pm[3][col + 1]), pm[3][col + 2]);
  bool alive = ((fabsf(p0) + fabsf(p1)) > 0.01f) && ((fabsf(p2) + fabsf(p3)) > 0.01f);
  if (!alive) {
#pragma unroll
    for (int ch = 0; ch < NCH; ++ch) xn[base0 + ((size_t)ch << 16)] = 0.f;
  }
}

extern "C" void kernel_launch(void* const* d_in, const int* in_sizes, int n_in,
                              void* d_out, int out_size, void* d_ws, size_t ws_size,
                              hipStream_t stream) {
  const float* x    = (const float*)d_in[0];
  const float* w1   = (const float*)d_in[1];
  const float* b1   = (const float*)d_in[2];
  const float* w2   = (const float*)d_in[3];
  const float* b2   = (const float*)d_in[4];
  const float* w3   = (const float*)d_in[5];
  const float* b3   = (const float*)d_in[6];
  const float* w4   = (const float*)d_in[7];
  const float* mask = (const float*)d_in[8];

  float* wsf = (float*)d_ws;
  float* xn = (float*)d_out;

  hipFuncSetAttribute(reinterpret_cast<const void*>(nca_band_k),
                      hipFuncAttributeMaxDynamicSharedMemorySize, LDS_TOTAL);

  prep_k<<<178, 256, 0, stream>>>(w1, w2, w3, w4, b1, b2, b3, wsf);
  nca_band_k<<<256, 1024, LDS_TOTAL, stream>>>(x, wsf, mask, xn);
  alive_scale_k<<<dim3(NH, NB), 256, 0, stream>>>(x, xn);
}

// Round 22
// 193.833 us; speedup vs baseline: 1.5118x; 1.5118x over previous
//
#include <hip/hip_runtime.h>

typedef _Float16 f16;
typedef f16 f16x8 __attribute__((ext_vector_type(8)));
typedef __fp16 h2v __attribute__((ext_vector_type(2)));
typedef float f32x4 __attribute__((ext_vector_type(4)));
typedef float f32x16 __attribute__((ext_vector_type(16)));
typedef unsigned int uint;
typedef unsigned short ushort;
typedef unsigned long long ull;

#define NCH 16
#define NB 32
#define NH 256
#define NW 256
#define HW 65536
#define CHW 1048576

#define BIAS_BYTE 90112
#define WS_BYTES 91648
#define BAND_ROWS 5
#define STAGE_ROWS 7
#define XBAND_OFF WS_BYTES                   // 91648
#define XBAND_BYTES (STAGE_ROWS*256*32)      // 57344
#define LIST_OFF (XBAND_OFF + XBAND_BYTES)   // 148992
#define LIST_MAX (BAND_ROWS*256)             // 1280
#define FLAG_OFF (LIST_OFF + LIST_MAX*2)     // 151552
#define CTR_OFF (FLAG_OFF + 1280)            // 152832
#define LDS_TOTAL (CTR_OFF + 16)             // 152848
#define NBANDS_PER_IMG 52                    // ceil(256/5)
#define NBANDS_TOTAL (NB*NBANDS_PER_IMG)     // 1664

__global__ void prep_k(const float* __restrict__ w1, const float* __restrict__ w2,
                       const float* __restrict__ w3, const float* __restrict__ w4,
                       const float* __restrict__ b1, const float* __restrict__ b2,
                       const float* __restrict__ b3, float* __restrict__ wsf) {
  f16* wf = (f16*)wsf;
  int id = blockIdx.x * 256 + threadIdx.x;
  if (id < 8192) {
    int j = id & 7, l = (id >> 3) & 63, mt = (id >> 9) & 3, kt = id >> 11;
    int o = mt * 32 + (l & 31), c = kt * 16 + (l >> 5) * 8 + j;
    wf[id] = (f16)w1[o * 64 + c];
  } else if (id < 24576) {
    int t = id - 8192;
    int j = t & 7, l = (t >> 3) & 63, mt = (t >> 9) & 3, kt = t >> 11;
    int o = mt * 32 + (l & 31), c = kt * 16 + (l >> 5) * 8 + j;
    wf[8192 + t] = (f16)w2[o * 128 + c];
  } else if (id < 40960) {
    int t = id - 24576;
    int j = t & 7, l = (t >> 3) & 63, mt = (t >> 9) & 3, kt = t >> 11;
    int o = mt * 32 + (l & 31), c = kt * 16 + (l >> 5) * 8 + j;
    wf[24576 + t] = (f16)w3[o * 128 + c];
  } else if (id < 45056) {
    int t = id - 40960;
    int j = t & 7, l = (t >> 3) & 63, kt = t >> 9;
    int m = l & 31, hh = l >> 5;
    int c = kt * 16 + hh * 8 + j;
    wf[40960 + t] = (m < 16) ? (f16)w4[m * 128 + c] : (f16)0.f;
  } else if (id < 45440) {
    int t = id - 45056;
    int r = t & 15, hh = (t >> 4) & 1, mt = (t >> 5) & 3, ly = t >> 7;
    const float* bb = (ly == 0) ? b1 : (ly == 1) ? b2 : b3;
    ((float*)((unsigned char*)wsf + BIAS_BYTE))[t] =
        bb[mt * 32 + (r & 3) + 8 * (r >> 2) + 4 * hh];
  }
}

__device__ __forceinline__ void pl32swap(uint& a, uint& b) {
  asm volatile("v_permlane32_swap_b32 %0, %1" : "+v"(a), "+v"(b));
}

__device__ __forceinline__ f16x8 mk8(uint a, uint b, uint c, uint d) {
  union { uint u[4]; f16x8 v; } z;
  z.u[0] = a; z.u[1] = b; z.u[2] = c; z.u[3] = d;
  return z.v;
}

template <int NKT>
__device__ __forceinline__ void gemm_half(const unsigned char* __restrict__ smem,
                                          int wfFragBase, int biasFloatOff, int lane, int hi,
                                          const f16x8* __restrict__ B, f32x16 acc[4]) {
#pragma unroll
  for (int mt = 0; mt < 4; ++mt) {
    const f32x16* bp =
        (const f32x16*)(smem + BIAS_BYTE + 4 * (biasFloatOff + (mt * 2 + hi) * 16));
    acc[mt] = *bp;
  }
  const f16x8* A = (const f16x8*)smem + wfFragBase + lane;
  __builtin_amdgcn_s_setprio(1);
#pragma unroll
  for (int kt = 0; kt < NKT; ++kt) {
#pragma unroll
    for (int mt = 0; mt < 4; ++mt) {
      f16x8 a = A[(kt * 4 + mt) * 64];
      acc[mt] = __builtin_amdgcn_mfma_f32_32x32x16_f16(a, B[kt], acc[mt], 0, 0, 0);
    }
  }
  __builtin_amdgcn_s_setprio(0);
}

__device__ __forceinline__ void epilogue_swap(const f32x16 acc[4], f16x8 Bn[8]) {
  uint w[32];
  const h2v c001 = {(__fp16)0.01f, (__fp16)0.01f};
#pragma unroll
  for (int mt = 0; mt < 4; ++mt) {
#pragma unroll
    for (int i = 0; i < 8; ++i) {
      h2v u = __builtin_amdgcn_cvt_pkrtz(acc[mt][2 * i], acc[mt][2 * i + 1]);
      h2v s = u * c001;
      h2v m = __builtin_elementwise_max(u, s);
      w[mt * 8 + i] = __builtin_bit_cast(uint, m);
    }
  }
#pragma unroll
  for (int kt = 0; kt < 8; ++kt) {
    int mt = kt >> 1, sub = kt & 1;
    int W = mt * 8 + sub * 4;
    uint a0 = w[W], a1 = w[W + 1], a2 = w[W + 2], a3 = w[W + 3];
    pl32swap(a0, a2);
    pl32swap(a1, a3);
    Bn[kt] = mk8(a0, a1, a2, a3);
  }
}

// perception from f16 band: 9 ds_read_b128; slot: half=(ch>>1)&1, j=(ch>>2)*2+(ch&1)
// byte addr = (sr*256+col)*32 + ((half ^ (col&1))<<4) + j*2
__device__ __forceinline__ void perc_band(const unsigned char* __restrict__ xband,
                                          int rl, int c, int hi, f16x8 B1h[4]) {
  const bool fL = c > 0, fR = c < NW - 1;
  const int cm = fL ? c - 1 : c, cp2 = fR ? c + 1 : c;
  const int swm = (hi ^ (cm & 1)) << 4;
  const int swc = (hi ^ (c & 1)) << 4;
  const int swp = (hi ^ (cp2 & 1)) << 4;
  union U4 { uint4 u; f16 hh[8]; };
  U4 q[9];
#pragma unroll
  for (int dr = 0; dr < 3; ++dr) {
    const unsigned char* rowp = xband + (size_t)(rl + dr) * 256 * 32;
    q[dr * 3 + 0].u = *(const uint4*)(rowp + cm * 32 + swm);
    q[dr * 3 + 1].u = *(const uint4*)(rowp + c * 32 + swc);
    q[dr * 3 + 2].u = *(const uint4*)(rowp + cp2 * 32 + swp);
  }
  uint yw[16];
#pragma unroll
  for (int j = 0; j < 8; ++j) {
    float v00 = (float)q[0].hh[j], v01 = (float)q[1].hh[j], v02 = (float)q[2].hh[j];
    float v10 = (float)q[3].hh[j], v11 = (float)q[4].hh[j], v12 = (float)q[5].hh[j];
    float v20 = (float)q[6].hh[j], v21 = (float)q[7].hh[j], v22 = (float)q[8].hh[j];
    if (!fL) { v00 = 0.f; v10 = 0.f; v20 = 0.f; }
    if (!fR) { v02 = 0.f; v12 = 0.f; v22 = 0.f; }
    float rs0 = v00 + v01 + v02, rs2 = v20 + v21 + v22;
    float fsx = (v02 - v00) + (v22 - v20) + 2.f * (v12 - v10);
    float fsy = (rs2 - rs0) + (v21 - v01);
    float flap = (rs0 + rs2 + v10 + v12) - 8.f * v11;
    h2v t0 = __builtin_amdgcn_cvt_pkrtz(v11, fsx);
    h2v t1 = __builtin_amdgcn_cvt_pkrtz(fsy, flap);
    int kt = j >> 1, cp = j & 1;
    yw[kt * 4 + cp * 2 + 0] = __builtin_bit_cast(uint, t0);
    yw[kt * 4 + cp * 2 + 1] = __builtin_bit_cast(uint, t1);
  }
#pragma unroll
  for (int kt = 0; kt < 4; ++kt)
    B1h[kt] = mk8(yw[kt * 4], yw[kt * 4 + 1], yw[kt * 4 + 2], yw[kt * 4 + 3]);
}

// Sparse band kernel (R20 skeleton): per band stage f16 band via per-(sr,col,half)
// register packing + ONE ds_write_b128; compact actives (+flags) -> barrier ->
// fused dense inactive copy + MLP on active batches.
__global__ __launch_bounds__(768, 1)
void nca_band_k(const float* __restrict__ x, const float* __restrict__ wsf,
                const float* __restrict__ mask, float* __restrict__ xn) {
  extern __shared__ unsigned char smem[];
  unsigned char* xband = smem + XBAND_OFF;
  ushort* list = (ushort*)(smem + LIST_OFF);
  unsigned char* flags = smem + FLAG_OFF;
  int* ctr = (int*)(smem + CTR_OFF);

  const int tid = threadIdx.x;
  const int lane = tid & 63;
  const int wv = tid >> 6;        // 0..11
  const int hi = lane >> 5;

  // ---- stage weights+bias once ----
  {
    const uint4* src = (const uint4*)wsf;
    uint4* dst = (uint4*)smem;
    for (int i = tid; i < WS_BYTES / 16; i += 768) dst[i] = src[i];
  }
  __syncthreads();

  for (int band = blockIdx.x; band < NBANDS_TOTAL; band += 256) {
    const int b = band / NBANDS_PER_IMG;
    const int r0 = (band - b * NBANDS_PER_IMG) * BAND_ROWS;
    const float* xb = x + (size_t)b * CHW;
    float* xnb = xn + (size_t)b * CHW;
    const float* mb = mask + (size_t)b * HW;

    if (tid == 0) *ctr = 0;
    __syncthreads();

    // ---- stage band: one thread per (sr, col, half) -> single b128 write ----
    for (int e = tid; e < STAGE_ROWS * 2 * 256; e += 768) {
      int col = e & 255;
      int pair = e >> 8;        // 0..13
      int sr = pair >> 1;
      int h = pair & 1;
      int gr = r0 - 1 + sr;
      union { f16 hh[8]; uint4 u; } rec;
      if ((unsigned)gr < (unsigned)NH) {
#pragma unroll
        for (int j = 0; j < 8; ++j) {
          int ch = ((j >> 1) << 2) | (h << 1) | (j & 1);
          rec.hh[j] = (f16)xb[((size_t)ch << 16) + (gr << 8) + col];
        }
      } else {
        rec.u.x = 0; rec.u.y = 0; rec.u.z = 0; rec.u.w = 0;
      }
      *(uint4*)(xband + (size_t)(sr * 256 + col) * 32 + ((h ^ (col & 1)) << 4)) = rec.u;
    }

    // ---- compact actives (+ flags): wave w (<5) handles row r0+w ----
    if (wv < BAND_ROWS) {
      int row = r0 + wv;
      if (row < NH) {
        ull bal[4];
        int c = 0;
#pragma unroll
        for (int k = 0; k < 4; ++k) {
          bool a = mb[(row << 8) + k * 64 + lane] > 0.f;
          flags[wv * 256 + k * 64 + lane] = a ? 1 : 0;
          bal[k] = __ballot(a);
          c += __popcll(bal[k]);
        }
        int base;
        if (lane == 0) base = atomicAdd(ctr, c);
        base = __shfl(base, 0);
#pragma unroll
        for (int k = 0; k < 4; ++k) {
          int rank = __popcll(bal[k] & ((1ull << lane) - 1));
          if ((bal[k] >> lane) & 1ull)
            list[base + rank] = (ushort)((wv << 8) | (k * 64 + lane));
          base += __popcll(bal[k]);
        }
      }
    }
    __syncthreads();

    // ---- fused dense inactive copy: xn = x where mask==0 (disjoint from MLP) ----
    for (int e = tid; e < BAND_ROWS * 16 * 256; e += 768) {
      int col = e & 255;
      int t2 = e >> 8;                    // 0..79
      int rl = t2 >> 4, ch = t2 & 15;
      int row = r0 + rl;
      if (row < NH && !flags[rl * 256 + col]) {
        size_t off = ((size_t)ch << 16) + (row << 8) + col;
        xnb[off] = xb[off];
      }
    }

    // ---- MLP on active batches ----
    const int n = *ctr;
    const int nbatch = (n + 31) >> 5;
    for (int k = wv; k < nbatch; k += 12) {
      int idx = k * 32 + (lane & 31);
      if (idx >= n) idx = n - 1;
      const int entry = list[idx];
      const int rl = entry >> 8, c = entry & 255;

      f16x8 B1[4];
      perc_band(xband, rl, c, hi, B1);

      f32x16 acc[4];
      f16x8 B2[8], B3[8], B4[8];
      gemm_half<4>(smem, 0, 0, lane, hi, B1, acc);
      epilogue_swap(acc, B2);
      gemm_half<8>(smem, 1024, 128, lane, hi, B2, acc);
      epilogue_swap(acc, B3);
      gemm_half<8>(smem, 3072, 256, lane, hi, B3, acc);
      epilogue_swap(acc, B4);

      f32x16 a4;
#pragma unroll
      for (int r = 0; r < 16; ++r) a4[r] = 0.f;
      {
        const f16x8* A4 = (const f16x8*)smem + 5120 + lane;
        __builtin_amdgcn_s_setprio(1);
#pragma unroll
        for (int kt = 0; kt < 8; ++kt)
          a4 = __builtin_amdgcn_mfma_f32_32x32x16_f16(A4[kt * 64], B4[kt], a4, 0, 0, 0);
        __builtin_amdgcn_s_setprio(0);
      }

      // update active px: mask==1 -> x + dy (exact f32 x re-read)
      {
        const int row = r0 + rl;
        const float* xrb = xb + (row << 8) + c;
        float* xob = xnb + (row << 8) + c;
#pragma unroll
        for (int r = 0; r < 8; ++r) {
          int ch = (r & 3) + 8 * (r >> 2) + 4 * hi;
          xob[(size_t)ch << 16] = xrb[(size_t)ch << 16] + a4[r];
        }
      }
    }
    __syncthreads();   // band LDS free for next iteration
  }
}

// alive factor: row-block with LDS horizontal-max sharing; zero dead pixels
__global__ void alive_scale_k(const float* __restrict__ x, float* __restrict__ xn) {
  __shared__ float pm[4][258];
  const int col = threadIdx.x;
  const int row = blockIdx.x;
  const int b = blockIdx.y;
  const float NEG = -3.0e38f;
  float v0 = NEG, v1 = NEG, v2 = NEG, v3 = NEG;
  const size_t base0 = (size_t)b * CHW + ((size_t)row << 8) + col;
#pragma unroll
  for (int dr = -1; dr <= 1; ++dr) {
    int rr = row + dr;
    if ((unsigned)rr < NH) {
      long o = (long)base0 + dr * NW;
      v0 = fmaxf(v0, x[o]);
      v1 = fmaxf(v1, x[o + HW]);
      v2 = fmaxf(v2, xn[o]);
      v3 = fmaxf(v3, xn[o + HW]);
    }
  }
  pm[0][col + 1] = v0;
  pm[1][col + 1] = v1;
  pm[2][col + 1] = v2;
  pm[3][col + 1] = v3;
  if (col == 0) {
#pragma unroll
    for (int f = 0; f < 4; ++f) { pm[f][0] = NEG; pm[f][257] = NEG; }
  }
  __syncthreads();
  float p0 = fmaxf(fmaxf(pm[0][col], pm[0][col + 1]), pm[0][col + 2]);
  float p1 = fmaxf(fmaxf(pm[1][col], pm[1][col + 1]), pm[1][col + 2]);
  float p2 = fmaxf(fmaxf(pm[2][col], pm[2][col + 1]), pm[2][col + 2]);
  float p3 = fmaxf(fmaxf(pm[3][col], pm[3][col + 1]), pm[3][col + 2]);
  bool alive = ((fabsf(p0) + fabsf(p1)) > 0.01f) && ((fabsf(p2) + fabsf(p3)) > 0.01f);
  if (!alive) {
#pragma unroll
    for (int ch = 0; ch < NCH; ++ch) xn[base0 + ((size_t)ch << 16)] = 0.f;
  }
}

extern "C" void kernel_launch(void* const* d_in, const int* in_sizes, int n_in,
                              void* d_out, int out_size, void* d_ws, size_t ws_size,
                              hipStream_t stream) {
  const float* x    = (const float*)d_in[0];
  const float* w1   = (const float*)d_in[1];
  const float* b1   = (const float*)d_in[2];
  const float* w2   = (const float*)d_in[3];
  const float* b2   = (const float*)d_in[4];
  const float* w3   = (const float*)d_in[5];
  const float* b3   = (const float*)d_in[6];
  const float* w4   = (const float*)d_in[7];
  const float* mask = (const float*)d_in[8];

  float* wsf = (float*)d_ws;
  float* xn = (float*)d_out;

  hipFuncSetAttribute(reinterpret_cast<const void*>(nca_band_k),
                      hipFuncAttributeMaxDynamicSharedMemorySize, LDS_TOTAL);

  prep_k<<<178, 256, 0, stream>>>(w1, w2, w3, w4, b1, b2, b3, wsf);
  nca_band_k<<<256, 768, LDS_TOTAL, stream>>>(x, wsf, mask, xn);
  alive_scale_k<<<dim3(NH, NB), 256, 0, stream>>>(x, xn);
}

// Round 23
// 190.008 us; speedup vs baseline: 1.5423x; 1.0201x over previous
//
#include <hip/hip_runtime.h>

typedef _Float16 f16;
typedef f16 f16x8 __attribute__((ext_vector_type(8)));
typedef __fp16 h2v __attribute__((ext_vector_type(2)));
typedef float f32x4 __attribute__((ext_vector_type(4)));
typedef float f32x16 __attribute__((ext_vector_type(16)));
typedef unsigned int uint;
typedef unsigned short ushort;
typedef unsigned long long ull;

#define NCH 16
#define NB 32
#define NH 256
#define NW 256
#define HW 65536
#define CHW 1048576

#define BIAS_BYTE 90112
#define WS_BYTES 91648
#define BAND_ROWS 5
#define STAGE_ROWS 7
#define XBAND_OFF WS_BYTES                   // 91648
#define XBAND_BYTES (STAGE_ROWS*256*32)      // 57344
#define LIST_OFF (XBAND_OFF + XBAND_BYTES)   // 148992 (2 buffers x 1280 ushort)
#define LIST_MAX (BAND_ROWS*256)             // 1280
#define NACT_OFF (LIST_OFF + 2*LIST_MAX*2)   // 154112
#define LDS_TOTAL (NACT_OFF + 16)            // 154128
#define NBANDS_PER_IMG 52                    // ceil(256/5)
#define NBANDS_TOTAL (NB*NBANDS_PER_IMG)     // 1664
#define NRECS (STAGE_ROWS*2*256)             // 3584

__global__ void prep_k(const float* __restrict__ w1, const float* __restrict__ w2,
                       const float* __restrict__ w3, const float* __restrict__ w4,
                       const float* __restrict__ b1, const float* __restrict__ b2,
                       const float* __restrict__ b3, float* __restrict__ wsf) {
  f16* wf = (f16*)wsf;
  int id = blockIdx.x * 256 + threadIdx.x;
  if (id < 8192) {
    int j = id & 7, l = (id >> 3) & 63, mt = (id >> 9) & 3, kt = id >> 11;
    int o = mt * 32 + (l & 31), c = kt * 16 + (l >> 5) * 8 + j;
    wf[id] = (f16)w1[o * 64 + c];
  } else if (id < 24576) {
    int t = id - 8192;
    int j = t & 7, l = (t >> 3) & 63, mt = (t >> 9) & 3, kt = t >> 11;
    int o = mt * 32 + (l & 31), c = kt * 16 + (l >> 5) * 8 + j;
    wf[8192 + t] = (f16)w2[o * 128 + c];
  } else if (id < 40960) {
    int t = id - 24576;
    int j = t & 7, l = (t >> 3) & 63, mt = (t >> 9) & 3, kt = t >> 11;
    int o = mt * 32 + (l & 31), c = kt * 16 + (l >> 5) * 8 + j;
    wf[24576 + t] = (f16)w3[o * 128 + c];
  } else if (id < 45056) {
    int t = id - 40960;
    int j = t & 7, l = (t >> 3) & 63, kt = t >> 9;
    int m = l & 31, hh = l >> 5;
    int c = kt * 16 + hh * 8 + j;
    wf[40960 + t] = (m < 16) ? (f16)w4[m * 128 + c] : (f16)0.f;
  } else if (id < 45440) {
    int t = id - 45056;
    int r = t & 15, hh = (t >> 4) & 1, mt = (t >> 5) & 3, ly = t >> 7;
    const float* bb = (ly == 0) ? b1 : (ly == 1) ? b2 : b3;
    ((float*)((unsigned char*)wsf + BIAS_BYTE))[t] =
        bb[mt * 32 + (r & 3) + 8 * (r >> 2) + 4 * hh];
  }
}

// dense base copy: xn = x (active px overwritten later by nca_band_k)
__global__ __launch_bounds__(256)
void copy_k(const float4* __restrict__ x4, float4* __restrict__ xn4) {
  const size_t total = (size_t)NB * CHW / 4;
  for (size_t i = (size_t)blockIdx.x * 256 + threadIdx.x; i < total; i += (size_t)2048 * 256)
    xn4[i] = x4[i];
}

__device__ __forceinline__ void pl32swap(uint& a, uint& b) {
  asm volatile("v_permlane32_swap_b32 %0, %1" : "+v"(a), "+v"(b));
}

__device__ __forceinline__ f16x8 mk8(uint a, uint b, uint c, uint d) {
  union { uint u[4]; f16x8 v; } z;
  z.u[0] = a; z.u[1] = b; z.u[2] = c; z.u[3] = d;
  return z.v;
}

template <int NKT>
__device__ __forceinline__ void gemm_half(const unsigned char* __restrict__ smem,
                                          int wfFragBase, int biasFloatOff, int lane, int hi,
                                          const f16x8* __restrict__ B, f32x16 acc[4]) {
#pragma unroll
  for (int mt = 0; mt < 4; ++mt) {
    const f32x16* bp =
        (const f32x16*)(smem + BIAS_BYTE + 4 * (biasFloatOff + (mt * 2 + hi) * 16));
    acc[mt] = *bp;
  }
  const f16x8* A = (const f16x8*)smem + wfFragBase + lane;
  __builtin_amdgcn_s_setprio(1);
#pragma unroll
  for (int kt = 0; kt < NKT; ++kt) {
#pragma unroll
    for (int mt = 0; mt < 4; ++mt) {
      f16x8 a = A[(kt * 4 + mt) * 64];
      acc[mt] = __builtin_amdgcn_mfma_f32_32x32x16_f16(a, B[kt], acc[mt], 0, 0, 0);
    }
  }
  __builtin_amdgcn_s_setprio(0);
}

__device__ __forceinline__ void epilogue_swap(const f32x16 acc[4], f16x8 Bn[8]) {
  uint w[32];
  const h2v c001 = {(__fp16)0.01f, (__fp16)0.01f};
#pragma unroll
  for (int mt = 0; mt < 4; ++mt) {
#pragma unroll
    for (int i = 0; i < 8; ++i) {
      h2v u = __builtin_amdgcn_cvt_pkrtz(acc[mt][2 * i], acc[mt][2 * i + 1]);
      h2v s = u * c001;
      h2v m = __builtin_elementwise_max(u, s);
      w[mt * 8 + i] = __builtin_bit_cast(uint, m);
    }
  }
#pragma unroll
  for (int kt = 0; kt < 8; ++kt) {
    int mt = kt >> 1, sub = kt & 1;
    int W = mt * 8 + sub * 4;
    uint a0 = w[W], a1 = w[W + 1], a2 = w[W + 2], a3 = w[W + 3];
    pl32swap(a0, a2);
    pl32swap(a1, a3);
    Bn[kt] = mk8(a0, a1, a2, a3);
  }
}

// perception from f16 band: 9 ds_read_b128; slot: half=(ch>>1)&1, j=(ch>>2)*2+(ch&1)
// byte addr = (sr*256+col)*32 + ((half ^ (col&1))<<4) + j*2
__device__ __forceinline__ void perc_band(const unsigned char* __restrict__ xband,
                                          int rl, int c, int hi, f16x8 B1h[4]) {
  const bool fL = c > 0, fR = c < NW - 1;
  const int cm = fL ? c - 1 : c, cp2 = fR ? c + 1 : c;
  const int swm = (hi ^ (cm & 1)) << 4;
  const int swc = (hi ^ (c & 1)) << 4;
  const int swp = (hi ^ (cp2 & 1)) << 4;
  union U4 { uint4 u; f16 hh[8]; };
  U4 q[9];
#pragma unroll
  for (int dr = 0; dr < 3; ++dr) {
    const unsigned char* rowp = xband + (size_t)(rl + dr) * 256 * 32;
    q[dr * 3 + 0].u = *(const uint4*)(rowp + cm * 32 + swm);
    q[dr * 3 + 1].u = *(const uint4*)(rowp + c * 32 + swc);
    q[dr * 3 + 2].u = *(const uint4*)(rowp + cp2 * 32 + swp);
  }
  uint yw[16];
#pragma unroll
  for (int j = 0; j < 8; ++j) {
    float v00 = (float)q[0].hh[j], v01 = (float)q[1].hh[j], v02 = (float)q[2].hh[j];
    float v10 = (float)q[3].hh[j], v11 = (float)q[4].hh[j], v12 = (float)q[5].hh[j];
    float v20 = (float)q[6].hh[j], v21 = (float)q[7].hh[j], v22 = (float)q[8].hh[j];
    if (!fL) { v00 = 0.f; v10 = 0.f; v20 = 0.f; }
    if (!fR) { v02 = 0.f; v12 = 0.f; v22 = 0.f; }
    float rs0 = v00 + v01 + v02, rs2 = v20 + v21 + v22;
    float fsx = (v02 - v00) + (v22 - v20) + 2.f * (v12 - v10);
    float fsy = (rs2 - rs0) + (v21 - v01);
    float flap = (rs0 + rs2 + v10 + v12) - 8.f * v11;
    h2v t0 = __builtin_amdgcn_cvt_pkrtz(v11, fsx);
    h2v t1 = __builtin_amdgcn_cvt_pkrtz(fsy, flap);
    int kt = j >> 1, cp = j & 1;
    yw[kt * 4 + cp * 2 + 0] = __builtin_bit_cast(uint, t0);
    yw[kt * 4 + cp * 2 + 1] = __builtin_bit_cast(uint, t1);
  }
#pragma unroll
  for (int kt = 0; kt < 4; ++kt)
    B1h[kt] = mk8(yw[kt * 4], yw[kt * 4 + 1], yw[kt * 4 + 2], yw[kt * 4 + 3]);
}

// load the 8 channels of one staging record (coalesced per wave) into a uint4
__device__ __forceinline__ uint4 load_rec(const float* __restrict__ xb, int r0, int e) {
  int col = e & 255;
  int pair = e >> 8;
  int sr = pair >> 1, h = pair & 1;
  int gr = r0 - 1 + sr;
  union { f16 hh[8]; uint4 u; } rc;
  if ((unsigned)gr < (unsigned)NH) {
#pragma unroll
    for (int j = 0; j < 8; ++j) {
      int ch = ((j >> 1) << 2) | (h << 1) | (j & 1);
      rc.hh[j] = (f16)xb[((size_t)ch << 16) + (gr << 8) + col];
    }
  } else {
    rc.u.x = 0; rc.u.y = 0; rc.u.z = 0; rc.u.w = 0;
  }
  return rc.u;
}

__device__ __forceinline__ void write_rec(unsigned char* __restrict__ xband, int e, uint4 r) {
  int col = e & 255;
  int pair = e >> 8;
  int sr = pair >> 1, h = pair & 1;
  *(uint4*)(xband + (size_t)(sr * 256 + col) * 32 + ((h ^ (col & 1)) << 4)) = r;
}

// compact one row's mask values (in regs) into list + ctr
__device__ __forceinline__ void compact_row(const float mv[4], int wv, int lane, int row,
                                            ushort* __restrict__ list,
                                            int* __restrict__ ctr) {
  if (row >= NH) return;
  ull bal[4];
  int c = 0;
#pragma unroll
  for (int k = 0; k < 4; ++k) {
    bool a = mv[k] > 0.f;
    bal[k] = __ballot(a);
    c += __popcll(bal[k]);
  }
  int base;
  if (lane == 0) base = atomicAdd(ctr, c);
  base = __shfl(base, 0);
#pragma unroll
  for (int k = 0; k < 4; ++k) {
    int rank = __popcll(bal[k] & ((1ull << lane) - 1));
    if ((bal[k] >> lane) & 1ull)
      list[base + rank] = (ushort)((wv << 8) | (k * 64 + lane));
    base += __popcll(bal[k]);
  }
}

__global__ __launch_bounds__(768, 1)
void nca_band_k(const float* __restrict__ x, const float* __restrict__ wsf,
                const float* __restrict__ mask, float* __restrict__ xn) {
  extern __shared__ unsigned char smem[];
  unsigned char* xband = smem + XBAND_OFF;
  ushort* listbuf = (ushort*)(smem + LIST_OFF);
  int* nacts = (int*)(smem + NACT_OFF);

  const int tid = threadIdx.x;
  const int lane = tid & 63;
  const int wv = tid >> 6;        // 0..11
  const int hi = lane >> 5;

  // ---- stage weights+bias once ----
  {
    const uint4* src = (const uint4*)wsf;
    uint4* dst = (uint4*)smem;
    for (int i = tid; i < WS_BYTES / 16; i += 768) dst[i] = src[i];
  }
  if (tid < 2) nacts[tid] = 0;
  __syncthreads();

  // ---- prologue: stage + compact band0 (buffer 0) ----
  {
    const int band = blockIdx.x;
    const int b = band / NBANDS_PER_IMG, r0 = (band % NBANDS_PER_IMG) * BAND_ROWS;
    const float* xb = x + (size_t)b * CHW;
    for (int e = tid; e < NRECS; e += 768) write_rec(xband, e, load_rec(xb, r0, e));
    if (wv < BAND_ROWS) {
      int row = r0 + wv;
      float mv[4] = {0.f, 0.f, 0.f, 0.f};
      if (row < NH) {
        const float* mb = mask + (size_t)b * HW;
#pragma unroll
        for (int k = 0; k < 4; ++k) mv[k] = mb[(row << 8) + k * 64 + lane];
      }
      compact_row(mv, wv, lane, row, listbuf, &nacts[0]);
    }
  }
  __syncthreads();

  for (int band = blockIdx.x, t = 0; band < NBANDS_TOTAL; band += 256, ++t) {
    const int lb = t & 1;
    const int b = band / NBANDS_PER_IMG, r0 = (band % NBANDS_PER_IMG) * BAND_ROWS;
    const float* xb = x + (size_t)b * CHW;
    float* xnb = xn + (size_t)b * CHW;
    const ushort* list = listbuf + lb * LIST_MAX;
    const int n = nacts[lb];

    // ---- T14: issue next band's staging loads into registers (24 VGPR) ----
    const int nxt = band + 256;
    const bool hasNext = nxt < NBANDS_TOTAL;
    uint4 rec[5];
    float nmv[4] = {0.f, 0.f, 0.f, 0.f};
    int nr0 = 0;
    if (hasNext) {
      const int b2 = nxt / NBANDS_PER_IMG;
      nr0 = (nxt % NBANDS_PER_IMG) * BAND_ROWS;
      const float* nxb = x + (size_t)b2 * CHW;
#pragma unroll
      for (int i = 0; i < 5; ++i) {
        int e = tid + i * 768;
        if (e < NRECS) rec[i] = load_rec(nxb, nr0, e);
      }
      if (wv < BAND_ROWS) {
        int row = nr0 + wv;
        if (row < NH) {
          const float* nmb = mask + (size_t)(nxt / NBANDS_PER_IMG) * HW;
#pragma unroll
          for (int k = 0; k < 4; ++k) nmv[k] = nmb[(row << 8) + k * 64 + lane];
        }
      }
    }
    __builtin_amdgcn_sched_barrier(0);   // pin prefetch issue before compute

    // ---- MLP on current band's active batches ----
    if (n > 0) {
      const int nbatch = (n + 31) >> 5;
      for (int k = wv; k < nbatch; k += 12) {
        int idx = k * 32 + (lane & 31);
        if (idx >= n) idx = n - 1;
        const int entry = list[idx];
        const int rl = entry >> 8, c = entry & 255;

        f16x8 B1[4];
        perc_band(xband, rl, c, hi, B1);

        f32x16 acc[4];
        f16x8 B2[8], B3[8], B4[8];
        gemm_half<4>(smem, 0, 0, lane, hi, B1, acc);
        epilogue_swap(acc, B2);
        gemm_half<8>(smem, 1024, 128, lane, hi, B2, acc);
        epilogue_swap(acc, B3);
        gemm_half<8>(smem, 3072, 256, lane, hi, B3, acc);
        epilogue_swap(acc, B4);

        f32x16 a4;
#pragma unroll
        for (int r = 0; r < 16; ++r) a4[r] = 0.f;
        {
          const f16x8* A4 = (const f16x8*)smem + 5120 + lane;
          __builtin_amdgcn_s_setprio(1);
#pragma unroll
          for (int kt = 0; kt < 8; ++kt)
            a4 = __builtin_amdgcn_mfma_f32_32x32x16_f16(A4[kt * 64], B4[kt], a4, 0, 0, 0);
          __builtin_amdgcn_s_setprio(0);
        }

        // update active px: mask==1 -> x + dy (exact f32 x re-read)
        {
          const int row = r0 + rl;
          const float* xrb = xb + (row << 8) + c;
          float* xob = xnb + (row << 8) + c;
#pragma unroll
          for (int r = 0; r < 8; ++r) {
            int ch = (r & 3) + 8 * (r >> 2) + 4 * hi;
            xob[(size_t)ch << 16] = xrb[(size_t)ch << 16] + a4[r];
          }
        }
      }
    }

    if (tid == 0) nacts[lb ^ 1] = 0;   // reset before barrier; compact after
    __syncthreads();                    // xband/list reads done, reset visible

    // ---- write prefetched records + compact next band ----
    if (hasNext) {
#pragma unroll
      for (int i = 0; i < 5; ++i) {
        int e = tid + i * 768;
        if (e < NRECS) write_rec(xband, e, rec[i]);
      }
      if (wv < BAND_ROWS)
        compact_row(nmv, wv, lane, nr0 + wv, listbuf + (lb ^ 1) * LIST_MAX,
                    &nacts[lb ^ 1]);
      __syncthreads();                 // next band's xband + list ready
    }
  }
}

// alive factor: row-block with LDS horizontal-max sharing; zero dead pixels
__global__ void alive_scale_k(const float* __restrict__ x, float* __restrict__ xn) {
  __shared__ float pm[4][258];
  const int col = threadIdx.x;
  const int row = blockIdx.x;
  const int b = blockIdx.y;
  const float NEG = -3.0e38f;
  float v0 = NEG, v1 = NEG, v2 = NEG, v3 = NEG;
  const size_t base0 = (size_t)b * CHW + ((size_t)row << 8) + col;
#pragma unroll
  for (int dr = -1; dr <= 1; ++dr) {
    int rr = row + dr;
    if ((unsigned)rr < NH) {
      long o = (long)base0 + dr * NW;
      v0 = fmaxf(v0, x[o]);
      v1 = fmaxf(v1, x[o + HW]);
      v2 = fmaxf(v2, xn[o]);
      v3 = fmaxf(v3, xn[o + HW]);
    }
  }
  pm[0][col + 1] = v0;
  pm[1][col + 1] = v1;
  pm[2][col + 1] = v2;
  pm[3][col + 1] = v3;
  if (col == 0) {
#pragma unroll
    for (int f = 0; f < 4; ++f) { pm[f][0] = NEG; pm[f][257] = NEG; }
  }
  __syncthreads();
  float p0 = fmaxf(fmaxf(pm[0][col], pm[0][col + 1]), pm[0][col + 2]);
  float p1 = fmaxf(fmaxf(pm[1][col], pm[1][col + 1]), pm[1][col + 2]);
  float p2 = fmaxf(fmaxf(pm[2][col], pm[2][col + 1]), pm[2][col + 2]);
  float p3 = fmaxf(fmaxf(pm[3][col], pm[3][col + 1]), pm[3][col + 2]);
  bool alive = ((fabsf(p0) + fabsf(p1)) > 0.01f) && ((fabsf(p2) + fabsf(p3)) > 0.01f);
  if (!alive) {
#pragma unroll
    for (int ch = 0; ch < NCH; ++ch) xn[base0 + ((size_t)ch << 16)] = 0.f;
  }
}

extern "C" void kernel_launch(void* const* d_in, const int* in_sizes, int n_in,
                              void* d_out, int out_size, void* d_ws, size_t ws_size,
                              hipStream_t stream) {
  const float* x    = (const float*)d_in[0];
  const float* w1   = (const float*)d_in[1];
  const float* b1   = (const float*)d_in[2];
  const float* w2   = (const float*)d_in[3];
  const float* b2   = (const float*)d_in[4];
  const float* w3   = (const float*)d_in[5];
  const float* b3   = (const float*)d_in[6];
  const float* w4   = (const float*)d_in[7];
  const float* mask = (const float*)d_in[8];

  float* wsf = (float*)d_ws;
  float* xn = (float*)d_out;

  hipFuncSetAttribute(reinterpret_cast<const void*>(nca_band_k),
                      hipFuncAttributeMaxDynamicSharedMemorySize, LDS_TOTAL);

  prep_k<<<178, 256, 0, stream>>>(w1, w2, w3, w4, b1, b2, b3, wsf);
  copy_k<<<2048, 256, 0, stream>>>((const float4*)x, (float4*)xn);
  nca_band_k<<<256, 768, LDS_TOTAL, stream>>>(x, wsf, mask, xn);
  alive_scale_k<<<dim3(NH, NB), 256, 0, stream>>>(x, xn);
}

// Round 24
// 186.447 us; speedup vs baseline: 1.5717x; 1.0191x over previous
//
#include <hip/hip_runtime.h>

typedef _Float16 f16;
typedef f16 f16x8 __attribute__((ext_vector_type(8)));
typedef __fp16 h2v __attribute__((ext_vector_type(2)));
typedef float f32x4 __attribute__((ext_vector_type(4)));
typedef float f32x16 __attribute__((ext_vector_type(16)));
typedef unsigned int uint;
typedef unsigned short ushort;
typedef unsigned long long ull;

#define NCH 16
#define NB 32
#define NH 256
#define NW 256
#define HW 65536
#define CHW 1048576

#define BIAS_BYTE 90112
#define WS_BYTES 91648
#define BAND_ROWS 5
#define STAGE_ROWS 7
#define XBAND_OFF WS_BYTES                   // 91648
#define XBAND_BYTES (STAGE_ROWS*256*32)      // 57344
#define LIST_OFF (XBAND_OFF + XBAND_BYTES)   // 148992
#define LIST_MAX (BAND_ROWS*256)             // 1280
#define CTR_OFF (LIST_OFF + LIST_MAX*2)      // 151552
#define LDS_TOTAL (CTR_OFF + 16)             // 151568
#define NBANDS_PER_IMG 52                    // ceil(256/5)
#define NBANDS_TOTAL (NB*NBANDS_PER_IMG)     // 1664

__global__ void prep_k(const float* __restrict__ w1, const float* __restrict__ w2,
                       const float* __restrict__ w3, const float* __restrict__ w4,
                       const float* __restrict__ b1, const float* __restrict__ b2,
                       const float* __restrict__ b3, float* __restrict__ wsf) {
  f16* wf = (f16*)wsf;
  int id = blockIdx.x * 256 + threadIdx.x;
  if (id < 8192) {
    int j = id & 7, l = (id >> 3) & 63, mt = (id >> 9) & 3, kt = id >> 11;
    int o = mt * 32 + (l & 31), c = kt * 16 + (l >> 5) * 8 + j;
    wf[id] = (f16)w1[o * 64 + c];
  } else if (id < 24576) {
    int t = id - 8192;
    int j = t & 7, l = (t >> 3) & 63, mt = (t >> 9) & 3, kt = t >> 11;
    int o = mt * 32 + (l & 31), c = kt * 16 + (l >> 5) * 8 + j;
    wf[8192 + t] = (f16)w2[o * 128 + c];
  } else if (id < 40960) {
    int t = id - 24576;
    int j = t & 7, l = (t >> 3) & 63, mt = (t >> 9) & 3, kt = t >> 11;
    int o = mt * 32 + (l & 31), c = kt * 16 + (l >> 5) * 8 + j;
    wf[24576 + t] = (f16)w3[o * 128 + c];
  } else if (id < 45056) {
    int t = id - 40960;
    int j = t & 7, l = (t >> 3) & 63, kt = t >> 9;
    int m = l & 31, hh = l >> 5;
    int c = kt * 16 + hh * 8 + j;
    wf[40960 + t] = (m < 16) ? (f16)w4[m * 128 + c] : (f16)0.f;
  } else if (id < 45440) {
    int t = id - 45056;
    int r = t & 15, hh = (t >> 4) & 1, mt = (t >> 5) & 3, ly = t >> 7;
    const float* bb = (ly == 0) ? b1 : (ly == 1) ? b2 : b3;
    ((float*)((unsigned char*)wsf + BIAS_BYTE))[t] =
        bb[mt * 32 + (r & 3) + 8 * (r >> 2) + 4 * hh];
  }
}

__device__ __forceinline__ void pl32swap(uint& a, uint& b) {
  asm volatile("v_permlane32_swap_b32 %0, %1" : "+v"(a), "+v"(b));
}

__device__ __forceinline__ f16x8 mk8(uint a, uint b, uint c, uint d) {
  union { uint u[4]; f16x8 v; } z;
  z.u[0] = a; z.u[1] = b; z.u[2] = c; z.u[3] = d;
  return z.v;
}

template <int NKT>
__device__ __forceinline__ void gemm_half(const unsigned char* __restrict__ smem,
                                          int wfFragBase, int biasFloatOff, int lane, int hi,
                                          const f16x8* __restrict__ B, f32x16 acc[4]) {
#pragma unroll
  for (int mt = 0; mt < 4; ++mt) {
    const f32x16* bp =
        (const f32x16*)(smem + BIAS_BYTE + 4 * (biasFloatOff + (mt * 2 + hi) * 16));
    acc[mt] = *bp;
  }
  const f16x8* A = (const f16x8*)smem + wfFragBase + lane;
  __builtin_amdgcn_s_setprio(1);
#pragma unroll
  for (int kt = 0; kt < NKT; ++kt) {
#pragma unroll
    for (int mt = 0; mt < 4; ++mt) {
      f16x8 a = A[(kt * 4 + mt) * 64];
      acc[mt] = __builtin_amdgcn_mfma_f32_32x32x16_f16(a, B[kt], acc[mt], 0, 0, 0);
    }
  }
  __builtin_amdgcn_s_setprio(0);
}

__device__ __forceinline__ void epilogue_swap(const f32x16 acc[4], f16x8 Bn[8]) {
  uint w[32];
  const h2v c001 = {(__fp16)0.01f, (__fp16)0.01f};
#pragma unroll
  for (int mt = 0; mt < 4; ++mt) {
#pragma unroll
    for (int i = 0; i < 8; ++i) {
      h2v u = __builtin_amdgcn_cvt_pkrtz(acc[mt][2 * i], acc[mt][2 * i + 1]);
      h2v s = u * c001;
      h2v m = __builtin_elementwise_max(u, s);
      w[mt * 8 + i] = __builtin_bit_cast(uint, m);
    }
  }
#pragma unroll
  for (int kt = 0; kt < 8; ++kt) {
    int mt = kt >> 1, sub = kt & 1;
    int W = mt * 8 + sub * 4;
    uint a0 = w[W], a1 = w[W + 1], a2 = w[W + 2], a3 = w[W + 3];
    pl32swap(a0, a2);
    pl32swap(a1, a3);
    Bn[kt] = mk8(a0, a1, a2, a3);
  }
}

// perception from f16 band: 9 ds_read_b128; slot: half=(ch>>1)&1, j=(ch>>2)*2+(ch&1)
// byte addr = (sr*256+col)*32 + ((half ^ (col&1))<<4) + j*2
__device__ __forceinline__ void perc_band(const unsigned char* __restrict__ xband,
                                          int rl, int c, int hi, f16x8 B1h[4]) {
  const bool fL = c > 0, fR = c < NW - 1;
  const int cm = fL ? c - 1 : c, cp2 = fR ? c + 1 : c;
  const int swm = (hi ^ (cm & 1)) << 4;
  const int swc = (hi ^ (c & 1)) << 4;
  const int swp = (hi ^ (cp2 & 1)) << 4;
  union U4 { uint4 u; f16 hh[8]; };
  U4 q[9];
#pragma unroll
  for (int dr = 0; dr < 3; ++dr) {
    const unsigned char* rowp = xband + (size_t)(rl + dr) * 256 * 32;
    q[dr * 3 + 0].u = *(const uint4*)(rowp + cm * 32 + swm);
    q[dr * 3 + 1].u = *(const uint4*)(rowp + c * 32 + swc);
    q[dr * 3 + 2].u = *(const uint4*)(rowp + cp2 * 32 + swp);
  }
  uint yw[16];
#pragma unroll
  for (int j = 0; j < 8; ++j) {
    float v00 = (float)q[0].hh[j], v01 = (float)q[1].hh[j], v02 = (float)q[2].hh[j];
    float v10 = (float)q[3].hh[j], v11 = (float)q[4].hh[j], v12 = (float)q[5].hh[j];
    float v20 = (float)q[6].hh[j], v21 = (float)q[7].hh[j], v22 = (float)q[8].hh[j];
    if (!fL) { v00 = 0.f; v10 = 0.f; v20 = 0.f; }
    if (!fR) { v02 = 0.f; v12 = 0.f; v22 = 0.f; }
    float rs0 = v00 + v01 + v02, rs2 = v20 + v21 + v22;
    float fsx = (v02 - v00) + (v22 - v20) + 2.f * (v12 - v10);
    float fsy = (rs2 - rs0) + (v21 - v01);
    float flap = (rs0 + rs2 + v10 + v12) - 8.f * v11;
    h2v t0 = __builtin_amdgcn_cvt_pkrtz(v11, fsx);
    h2v t1 = __builtin_amdgcn_cvt_pkrtz(fsy, flap);
    int kt = j >> 1, cp = j & 1;
    yw[kt * 4 + cp * 2 + 0] = __builtin_bit_cast(uint, t0);
    yw[kt * 4 + cp * 2 + 1] = __builtin_bit_cast(uint, t1);
  }
#pragma unroll
  for (int kt = 0; kt < 4; ++kt)
    B1h[kt] = mk8(yw[kt * 4], yw[kt * 4 + 1], yw[kt * 4 + 2], yw[kt * 4 + 3]);
}

// Sparse band kernel (R20-verbatim): stage f16 band via per-(sr,col,half) register
// packing + ONE ds_write_b128; compact actives -> barrier -> MLP on active batches.
__global__ __launch_bounds__(768, 1)
void nca_band_k(const float* __restrict__ x, const float* __restrict__ wsf,
                const float* __restrict__ mask, float* __restrict__ xn) {
  extern __shared__ unsigned char smem[];
  unsigned char* xband = smem + XBAND_OFF;
  ushort* list = (ushort*)(smem + LIST_OFF);
  int* ctr = (int*)(smem + CTR_OFF);

  const int tid = threadIdx.x;
  const int lane = tid & 63;
  const int wv = tid >> 6;        // 0..11
  const int hi = lane >> 5;

  {
    const uint4* src = (const uint4*)wsf;
    uint4* dst = (uint4*)smem;
    for (int i = tid; i < WS_BYTES / 16; i += 768) dst[i] = src[i];
  }
  __syncthreads();

  for (int band = blockIdx.x; band < NBANDS_TOTAL; band += 256) {
    const int b = band / NBANDS_PER_IMG;
    const int r0 = (band - b * NBANDS_PER_IMG) * BAND_ROWS;
    const float* xb = x + (size_t)b * CHW;
    float* xnb = xn + (size_t)b * CHW;
    const float* mb = mask + (size_t)b * HW;

    if (tid == 0) *ctr = 0;
    __syncthreads();

    // stage band: one thread per (sr, col, half) -> single b128 write
    for (int e = tid; e < STAGE_ROWS * 2 * 256; e += 768) {
      int col = e & 255;
      int pair = e >> 8;
      int sr = pair >> 1;
      int h = pair & 1;
      int gr = r0 - 1 + sr;
      union { f16 hh[8]; uint4 u; } rec;
      if ((unsigned)gr < (unsigned)NH) {
#pragma unroll
        for (int j = 0; j < 8; ++j) {
          int ch = ((j >> 1) << 2) | (h << 1) | (j & 1);
          rec.hh[j] = (f16)xb[((size_t)ch << 16) + (gr << 8) + col];
        }
      } else {
        rec.u.x = 0; rec.u.y = 0; rec.u.z = 0; rec.u.w = 0;
      }
      *(uint4*)(xband + (size_t)(sr * 256 + col) * 32 + ((h ^ (col & 1)) << 4)) = rec.u;
    }

    // compact actives: wave w (<5) handles row r0+w
    if (wv < BAND_ROWS) {
      int row = r0 + wv;
      if (row < NH) {
        ull bal[4];
        int c = 0;
#pragma unroll
        for (int k = 0; k < 4; ++k) {
          bool a = mb[(row << 8) + k * 64 + lane] > 0.f;
          bal[k] = __ballot(a);
          c += __popcll(bal[k]);
        }
        int base;
        if (lane == 0) base = atomicAdd(ctr, c);
        base = __shfl(base, 0);
#pragma unroll
        for (int k = 0; k < 4; ++k) {
          int rank = __popcll(bal[k] & ((1ull << lane) - 1));
          if ((bal[k] >> lane) & 1ull)
            list[base + rank] = (ushort)((wv << 8) | (k * 64 + lane));
          base += __popcll(bal[k]);
        }
      }
    }
    __syncthreads();

    // MLP on active batches
    const int n = *ctr;
    const int nbatch = (n + 31) >> 5;
    for (int k = wv; k < nbatch; k += 12) {
      int idx = k * 32 + (lane & 31);
      if (idx >= n) idx = n - 1;
      const int entry = list[idx];
      const int rl = entry >> 8, c = entry & 255;

      f16x8 B1[4];
      perc_band(xband, rl, c, hi, B1);

      f32x16 acc[4];
      f16x8 B2[8], B3[8], B4[8];
      gemm_half<4>(smem, 0, 0, lane, hi, B1, acc);
      epilogue_swap(acc, B2);
      gemm_half<8>(smem, 1024, 128, lane, hi, B2, acc);
      epilogue_swap(acc, B3);
      gemm_half<8>(smem, 3072, 256, lane, hi, B3, acc);
      epilogue_swap(acc, B4);

      f32x16 a4;
#pragma unroll
      for (int r = 0; r < 16; ++r) a4[r] = 0.f;
      {
        const f16x8* A4 = (const f16x8*)smem + 5120 + lane;
        __builtin_amdgcn_s_setprio(1);
#pragma unroll
        for (int kt = 0; kt < 8; ++kt)
          a4 = __builtin_amdgcn_mfma_f32_32x32x16_f16(A4[kt * 64], B4[kt], a4, 0, 0, 0);
        __builtin_amdgcn_s_setprio(0);
      }

      {
        const int row = r0 + rl;
        const float* xrb = xb + (row << 8) + c;
        float* xob = xnb + (row << 8) + c;
#pragma unroll
        for (int r = 0; r < 8; ++r) {
          int ch = (r & 3) + 8 * (r >> 2) + 4 * hi;
          xob[(size_t)ch << 16] = xrb[(size_t)ch << 16] + a4[r];
        }
      }
    }
    __syncthreads();
  }
}

// Fused copy + alive-scale (runs AFTER nca_band_k):
//   sel = mask>0 ? xn : x  (xn of actives written by band_k; inactive xn==x)
//   pre_alive from x pools, post_alive from sel pools (ch0,ch1)
//   inactive px: xn = alive ? x : 0  (the copy)
//   active px:   if !alive, xn = 0   (else keep band_k's value)
__global__ __launch_bounds__(256)
void finish_k(const float* __restrict__ x, const float* __restrict__ mask,
              float* __restrict__ xn) {
  __shared__ float xp0[3][258], xp1[3][258], sp0[3][258], sp1[3][258];
  const int col = threadIdx.x;
  const int row = blockIdx.x;
  const int b = blockIdx.y;
  const float NEG = -3.0e38f;
  const float* xb = x + (size_t)b * CHW;
  float* xnb = xn + (size_t)b * CHW;
  const float* mb = mask + (size_t)b * HW;

  float mctr = 0.f;
#pragma unroll
  for (int dr = 0; dr < 3; ++dr) {
    int rr = row - 1 + dr;
    float x0 = NEG, x1 = NEG, s0 = NEG, s1 = NEG;
    if ((unsigned)rr < (unsigned)NH) {
      int off = (rr << 8) + col;
      float m = mb[off];
      x0 = xb[off];
      x1 = xb[HW + off];
      if (m > 0.f) {
        s0 = xnb[off];
        s1 = xnb[HW + off];
      } else {
        s0 = x0;
        s1 = x1;
      }
      if (dr == 1) mctr = m;
    }
    xp0[dr][col + 1] = x0;
    xp1[dr][col + 1] = x1;
    sp0[dr][col + 1] = s0;
    sp1[dr][col + 1] = s1;
  }
  if (col == 0) {
#pragma unroll
    for (int dr = 0; dr < 3; ++dr) {
      xp0[dr][0] = NEG; xp0[dr][257] = NEG;
      xp1[dr][0] = NEG; xp1[dr][257] = NEG;
      sp0[dr][0] = NEG; sp0[dr][257] = NEG;
      sp1[dr][0] = NEG; sp1[dr][257] = NEG;
    }
  }
  __syncthreads();

  float px0 = NEG, px1 = NEG, ps0 = NEG, ps1 = NEG;
#pragma unroll
  for (int dr = 0; dr < 3; ++dr) {
#pragma unroll
    for (int dc = 0; dc < 3; ++dc) {
      px0 = fmaxf(px0, xp0[dr][col + dc]);
      px1 = fmaxf(px1, xp1[dr][col + dc]);
      ps0 = fmaxf(ps0, sp0[dr][col + dc]);
      ps1 = fmaxf(ps1, sp1[dr][col + dc]);
    }
  }
  const bool pre = (fabsf(px0) + fabsf(px1)) > 0.01f;
  const bool post = (fabsf(ps0) + fabsf(ps1)) > 0.01f;
  const bool alive = pre && post;
  const bool active = mctr > 0.f;

  const size_t base = ((size_t)row << 8) + col;
  if (!active) {
    if (alive) {
#pragma unroll
      for (int ch = 0; ch < NCH; ++ch)
        xnb[base + ((size_t)ch << 16)] = xb[base + ((size_t)ch << 16)];
    } else {
#pragma unroll
      for (int ch = 0; ch < NCH; ++ch) xnb[base + ((size_t)ch << 16)] = 0.f;
    }
  } else if (!alive) {
#pragma unroll
    for (int ch = 0; ch < NCH; ++ch) xnb[base + ((size_t)ch << 16)] = 0.f;
  }
}

extern "C" void kernel_launch(void* const* d_in, const int* in_sizes, int n_in,
                              void* d_out, int out_size, void* d_ws, size_t ws_size,
                              hipStream_t stream) {
  const float* x    = (const float*)d_in[0];
  const float* w1   = (const float*)d_in[1];
  const float* b1   = (const float*)d_in[2];
  const float* w2   = (const float*)d_in[3];
  const float* b2   = (const float*)d_in[4];
  const float* w3   = (const float*)d_in[5];
  const float* b3   = (const float*)d_in[6];
  const float* w4   = (const float*)d_in[7];
  const float* mask = (const float*)d_in[8];

  float* wsf = (float*)d_ws;
  float* xn = (float*)d_out;

  hipFuncSetAttribute(reinterpret_cast<const void*>(nca_band_k),
                      hipFuncAttributeMaxDynamicSharedMemorySize, LDS_TOTAL);

  prep_k<<<178, 256, 0, stream>>>(w1, w2, w3, w4, b1, b2, b3, wsf);
  nca_band_k<<<256, 768, LDS_TOTAL, stream>>>(x, wsf, mask, xn);
  finish_k<<<dim3(NH, NB), 256, 0, stream>>>(x, mask, xn);
}